// Round 5
// baseline (93.952 us; speedup 1.0000x reference)
//
#include <hip/hip_runtime.h>

// Patlak/extended-Tofts signal model.
//
// TIMING PROBE (R3/R4/R5 resubmits — broker timeouts, never ran): kernel_launch
// launches the kernel TWICE back-to-back (second pass overwrites d_out with
// identical values; same work every call, graph-safe).
// dur(probe) - dur(R2=82.0us) ~= one kernel pass + launch overhead, which
// measures the kernel's true duration (it is hidden below the harness's 44us
// poison fills in rocprof top-5). The single-launch version is the final
// submission.
//
// Kernel: 4 pixels/thread (float4 in/out), t split into 2 chunks of 30
// (grid = 512 blocks, 2 waves/SIMD; fetch 8.4 MB + write 62.9 MB -> 11.3 us
// roofline @ 6.3 TB/s). Cp prefix-sum once per block via wave shfl-scan.
//
// St = (A - A*e) / (B - C*e),  e = exp(-P - 0.0225*Ct),
// Ct = vp*Cp[t] + (Ktrans*DELTT/60)*cumsum(Cp)[t]
// A = (1-cosFA*exp(-P))*S0, B = (1-exp(-P))+EPS, C = cosFA*(1-exp(-P))

#define HW_   (256 * 256)
#define NT_   60
#define TCH_  30          // t-chunk length (NT_/2)
#define PXT_  4           // pixels per thread

__global__ __launch_bounds__(256) void patlak_kernel(
    const float* __restrict__ params,   // (B, 2, H, W)
    const float* __restrict__ Cp,       // (B, T)
    const float* __restrict__ S0,       // (B, 1, H, W)
    const float* __restrict__ T1,       // (B, 1, H, W)
    float* __restrict__ out)            // (B, T, H, W)
{
    __shared__ float s_cp[NT_];
    __shared__ float s_ce[NT_];   // inclusive cumsum of Cp

    const int bid = blockIdx.x;       // 0..511
    const int b   = bid >> 7;         // 4 batches
    const int rem = bid & 127;
    const int c   = rem >> 6;         // t-chunk 0..1
    const int blk = rem & 63;         // pixel-block within image
    const int tid = threadIdx.x;

    // Cp row + inclusive prefix sum, once per block (wave-0 shfl scan).
    if (tid < 64) {
        float v = (tid < NT_) ? Cp[b * NT_ + tid] : 0.0f;
        float s = v;
        #pragma unroll
        for (int d = 1; d < 64; d <<= 1) {
            float u = __shfl_up(s, d, 64);
            if (tid >= d) s += u;
        }
        if (tid < NT_) { s_cp[tid] = v; s_ce[tid] = s; }
    }
    __syncthreads();

    const int p4 = (blk * 256 + tid) * PXT_;   // first of 4 consecutive pixels

    const float4 kt4 = *(const float4*)(params + (size_t)(b * 2 + 0) * HW_ + p4);
    const float4 vp4 = *(const float4*)(params + (size_t)(b * 2 + 1) * HW_ + p4);
    const float4 s04 = *(const float4*)(S0 + (size_t)b * HW_ + p4);
    const float4 t14 = *(const float4*)(T1 + (size_t)b * HW_ + p4);

    const float cosfa = 0.9848077530122080594f;  // cos(10 deg)

    float kD[PXT_], vp[PXT_], P[PXT_], A[PXT_], Bv[PXT_], Cv[PXT_];
    {
        const float kt_[4] = {kt4.x, kt4.y, kt4.z, kt4.w};
        const float vp_[4] = {vp4.x, vp4.y, vp4.z, vp4.w};
        const float s0_[4] = {s04.x, s04.y, s04.z, s04.w};
        const float t1_[4] = {t14.x, t14.y, t14.z, t14.w};
        #pragma unroll
        for (int i = 0; i < PXT_; ++i) {
            kD[i] = kt_[i] * (4.0f / 60.0f);        // Ktrans/60 * DELTT
            vp[i] = vp_[i];
            P[i]  = 5.0f / (t1_[i] + 1e-8f);        // TR/(T1+EPS)
            const float ep  = __expf(-P[i]);
            const float omp = 1.0f - ep;
            A[i]  = (1.0f - cosfa * ep) * s0_[i];
            Bv[i] = omp + 1e-8f;
            Cv[i] = cosfa * omp;
        }
    }

    const int t0 = c * TCH_;
    float* outp = out + ((size_t)b * NT_ + t0) * HW_ + p4;

    #pragma unroll 6
    for (int i = 0; i < TCH_; ++i) {
        const float cp = s_cp[t0 + i];
        const float ce = s_ce[t0 + i];
        float4 r;
        float res[PXT_];
        #pragma unroll
        for (int j = 0; j < PXT_; ++j) {
            const float Ct = vp[j] * cp + kD[j] * ce;
            const float e  = __expf(-P[j] - 0.0225f * Ct);  // R1*TR/1000 = 0.0225
            const float num = A[j] - A[j] * e;
            const float den = Bv[j] - Cv[j] * e;
            res[j] = num * __builtin_amdgcn_rcpf(den);
        }
        r.x = res[0]; r.y = res[1]; r.z = res[2]; r.w = res[3];
        *(float4*)outp = r;
        outp += HW_;
    }
}

extern "C" void kernel_launch(void* const* d_in, const int* in_sizes, int n_in,
                              void* d_out, int out_size, void* d_ws, size_t ws_size,
                              hipStream_t stream) {
    const float* params = (const float*)d_in[0];
    const float* Cp     = (const float*)d_in[1];
    const float* S0     = (const float*)d_in[2];
    const float* T1     = (const float*)d_in[3];
    float* out          = (float*)d_out;

    // 4 batches * 2 t-chunks * 64 pixel-blocks = 512 blocks of 256 threads.
    // PROBE: launched twice (identical output) to measure one kernel pass as
    // dur(probe) - dur(R2). Remove the second launch once kernel time is known.
    patlak_kernel<<<512, 256, 0, stream>>>(params, Cp, S0, T1, out);
    patlak_kernel<<<512, 256, 0, stream>>>(params, Cp, S0, T1, out);
}

// Round 6
// 81.472 us; speedup vs baseline: 1.1532x; 1.1532x over previous
//
#include <hip/hip_runtime.h>

// Patlak/extended-Tofts signal model — FINAL (single launch).
//
// Measured via the R5 double-launch probe: one kernel pass ~= 12.0 us
// (dur 82.0 -> 93.95 with a second identical launch), matching the
// write-roofline: 62.9 MB out + 8.4 MB in ~= 71 MB @ ~6 TB/s = ~11.3 us.
// The kernel runs at the same achievable HBM ceiling as the harness's own
// 268 MB fillBufferAligned (5.9-6.2 TB/s). Remaining dur_us (~70 us) is
// fixed harness reset overhead (poison fills + input restores).
//
// Structure: 4 pixels/thread (float4 in/out), t split into 2 chunks of 30
// (grid = 512 blocks of 256 threads, 2 waves/SIMD — the fill kernel proves
// HBM saturates even at ~2.6 waves/CU). Cp prefix-sum once per block via a
// wave-0 shfl inclusive scan, making all t-iterations independent.
//
// Math (hoisted per-pixel):
//   P = TR/(T1+EPS), expP = exp(-P)
//   A = (1 - cosFA*expP) * S0,  B = (1-expP)+EPS,  C = cosFA*(1-expP)
//   Ct = vp*Cp[t] + (Ktrans*DELTT/60)*cumsum(Cp)[t]
//   St = (A - A*e) / (B - C*e),  e = exp(-P - R1*(TR/1000)*Ct)
// __expf / v_rcp_f32 are safe: denominator in [0.98, 1] (P > 5 since
// T1 in [0,1)), absolute threshold 2e-2, measured absmax 3.9e-3.

#define HW_   (256 * 256)
#define NT_   60
#define TCH_  30          // t-chunk length (NT_/2)
#define PXT_  4           // pixels per thread

__global__ __launch_bounds__(256) void patlak_kernel(
    const float* __restrict__ params,   // (B, 2, H, W)
    const float* __restrict__ Cp,       // (B, T)
    const float* __restrict__ S0,       // (B, 1, H, W)
    const float* __restrict__ T1,       // (B, 1, H, W)
    float* __restrict__ out)            // (B, T, H, W)
{
    __shared__ float s_cp[NT_];
    __shared__ float s_ce[NT_];   // inclusive cumsum of Cp

    const int bid = blockIdx.x;       // 0..511
    const int b   = bid >> 7;         // 4 batches
    const int rem = bid & 127;
    const int c   = rem >> 6;         // t-chunk 0..1
    const int blk = rem & 63;         // pixel-block within image
    const int tid = threadIdx.x;

    // Cp row + inclusive prefix sum, once per block (wave-0 shfl scan).
    if (tid < 64) {
        float v = (tid < NT_) ? Cp[b * NT_ + tid] : 0.0f;
        float s = v;
        #pragma unroll
        for (int d = 1; d < 64; d <<= 1) {
            float u = __shfl_up(s, d, 64);
            if (tid >= d) s += u;
        }
        if (tid < NT_) { s_cp[tid] = v; s_ce[tid] = s; }
    }
    __syncthreads();

    const int p4 = (blk * 256 + tid) * PXT_;   // first of 4 consecutive pixels

    const float4 kt4 = *(const float4*)(params + (size_t)(b * 2 + 0) * HW_ + p4);
    const float4 vp4 = *(const float4*)(params + (size_t)(b * 2 + 1) * HW_ + p4);
    const float4 s04 = *(const float4*)(S0 + (size_t)b * HW_ + p4);
    const float4 t14 = *(const float4*)(T1 + (size_t)b * HW_ + p4);

    const float cosfa = 0.9848077530122080594f;  // cos(10 deg)

    float kD[PXT_], vp[PXT_], P[PXT_], A[PXT_], Bv[PXT_], Cv[PXT_];
    {
        const float kt_[4] = {kt4.x, kt4.y, kt4.z, kt4.w};
        const float vp_[4] = {vp4.x, vp4.y, vp4.z, vp4.w};
        const float s0_[4] = {s04.x, s04.y, s04.z, s04.w};
        const float t1_[4] = {t14.x, t14.y, t14.z, t14.w};
        #pragma unroll
        for (int i = 0; i < PXT_; ++i) {
            kD[i] = kt_[i] * (4.0f / 60.0f);        // Ktrans/60 * DELTT
            vp[i] = vp_[i];
            P[i]  = 5.0f / (t1_[i] + 1e-8f);        // TR/(T1+EPS)
            const float ep  = __expf(-P[i]);
            const float omp = 1.0f - ep;
            A[i]  = (1.0f - cosfa * ep) * s0_[i];
            Bv[i] = omp + 1e-8f;
            Cv[i] = cosfa * omp;
        }
    }

    const int t0 = c * TCH_;
    float* outp = out + ((size_t)b * NT_ + t0) * HW_ + p4;

    #pragma unroll 6
    for (int i = 0; i < TCH_; ++i) {
        const float cp = s_cp[t0 + i];
        const float ce = s_ce[t0 + i];
        float4 r;
        float res[PXT_];
        #pragma unroll
        for (int j = 0; j < PXT_; ++j) {
            const float Ct = vp[j] * cp + kD[j] * ce;
            const float e  = __expf(-P[j] - 0.0225f * Ct);  // R1*TR/1000 = 0.0225
            const float num = A[j] - A[j] * e;
            const float den = Bv[j] - Cv[j] * e;
            res[j] = num * __builtin_amdgcn_rcpf(den);
        }
        r.x = res[0]; r.y = res[1]; r.z = res[2]; r.w = res[3];
        *(float4*)outp = r;
        outp += HW_;
    }
}

extern "C" void kernel_launch(void* const* d_in, const int* in_sizes, int n_in,
                              void* d_out, int out_size, void* d_ws, size_t ws_size,
                              hipStream_t stream) {
    const float* params = (const float*)d_in[0];
    const float* Cp     = (const float*)d_in[1];
    const float* S0     = (const float*)d_in[2];
    const float* T1     = (const float*)d_in[3];
    float* out          = (float*)d_out;

    // 4 batches * 2 t-chunks * 64 pixel-blocks = 512 blocks of 256 threads.
    patlak_kernel<<<512, 256, 0, stream>>>(params, Cp, S0, T1, out);
}